// Round 6
// baseline (474.328 us; speedup 1.0000x reference)
//
#include <hip/hip_runtime.h>
#include <cstdint>
#include <cstddef>

// ---------------------------------------------------------------------------
// Episodic memory module (DMN) on MI355X — round 6.
//
// R5 post-mortem: xproj is now the top dispatch (71us) — latency-bound on the
// per-Mt facts load (exposed ~900cyc after each barrier), 2.6M LDS bank
// conflicts (16-way on fragbuf A-frag deposit, 8-way on the xrtrans scalar
// transpose), and one redundant barrier per Mt.
//
// R6 (xproj only; scores/scan/prep identical to R5):
//  * register double-buffer of the next facts tile (load issued right after
//    bar1, consumed next iteration -> HBM latency hidden behind MFMA+epilogue)
//  * fragbuf swizzle u^=(u>>6)  : 16-way write conflict -> uniform (free)
//  * xrtrans swizzle u^=((u>>4)&3): 8-way -> 4-way
//    (both ws stores unswizzle at copy time; ws layout/scores/scan untouched)
//  * 3 -> 2 barriers per Mt (bar3 redundant: bar1 of next iter orders the
//    xrtrans read-vs-write hazard; ldsbar waits lgkmcnt(0) per wave)
// ---------------------------------------------------------------------------

typedef __bf16 bf16_t;
typedef __attribute__((ext_vector_type(8))) __bf16 bf16x8;
typedef __attribute__((ext_vector_type(4))) __bf16 bf16x4;
typedef __attribute__((ext_vector_type(4))) float f32x4;

static __device__ __forceinline__ f32x4 mfma16(bf16x8 a, bf16x8 b, f32x4 c) {
  return __builtin_amdgcn_mfma_f32_16x16x32_bf16(a, b, c, 0, 0, 0);
}
static __device__ __forceinline__ float fast_rcp(float x) { return __builtin_amdgcn_rcpf(x); }
static __device__ __forceinline__ float sigmoid_f(float x) {
  return fast_rcp(1.f + exp2f(-1.44269504f * x));
}
static __device__ __forceinline__ float tanh_f(float x) {
  float e = exp2f(2.88539008f * x);
  return 1.f - 2.f * fast_rcp(e + 1.f);
}
static __device__ __forceinline__ unsigned short f2bf(float x) {
  __bf16 h = (__bf16)x;
  return __builtin_bit_cast(unsigned short, h);
}
// Workgroup barrier WITHOUT the vmcnt(0) drain __syncthreads() carries.
// All call sites are in wave-uniform control flow.
static __device__ __forceinline__ void ldsbar() {
  asm volatile("s_waitcnt lgkmcnt(0)\n\ts_barrier" ::: "memory");
}

// ws layout (bf16 element offsets).  B-fragment layout for a K x N matrix:
// elem(k,n) at ((kt*NT + nt)*64 + lane)*8 + j, kt=k/32, nt=n/16,
// lane=((k%32)/8)*16 + (n%16), j=k%8.
static constexpr size_t E_GRUK  = 0;                            // K=256 N=512
static constexpr size_t E_RKR   = 131072;                       // K=256 N=256
static constexpr size_t E_RKH   = 196608;
static constexpr size_t E_W1F   = 262144;                       // K=1024 N=64
static constexpr size_t E_WMF   = 327680;                       // K=768 N=256
static constexpr size_t E_XR    = 524288;                       // + b*131072 (A-frag)
static constexpr size_t E_XHC   = E_XR  + (size_t)128 * 131072; // + b*131072 (C order)
static constexpr size_t E_FACTS = E_XHC + (size_t)128 * 131072; // + b*131072 (A-frag)
static constexpr size_t E_END   = E_FACTS + (size_t)128 * 131072;
static constexpr size_t F_SCORES = 0;
static constexpr size_t F_MEM    = 65536;

__global__ void prep_weights(const float* __restrict__ gru_k,
                             const float* __restrict__ gru_rk,
                             const float* __restrict__ W1,
                             const float* __restrict__ Wm,
                             bf16_t* __restrict__ ws) {
  size_t idx = (size_t)blockIdx.x * 256 + threadIdx.x;
  if (idx >= 524288) return;
  size_t local; int NT, which;
  if (idx < 131072)      { local = idx;          NT = 32; which = 0; }
  else if (idx < 196608) { local = idx - 131072; NT = 16; which = 1; }
  else if (idx < 262144) { local = idx - 196608; NT = 16; which = 2; }
  else if (idx < 327680) { local = idx - 262144; NT = 4;  which = 3; }
  else                   { local = idx - 327680; NT = 16; which = 4; }
  int j    = (int)(local & 7);
  int lane = (int)((local >> 3) & 63);
  size_t rem = local >> 9;
  int nt = (int)(rem % NT);
  int kt = (int)(rem / NT);
  int k = kt * 32 + (lane >> 4) * 8 + j;
  int n = nt * 16 + (lane & 15);
  float v;
  switch (which) {
    case 0:  v = gru_k[(size_t)k * 768 + 256 + n]; break;
    case 1:  v = gru_rk[(size_t)k * 768 + 256 + n]; break;
    case 2:  v = gru_rk[(size_t)k * 768 + 512 + n]; break;
    case 3:  v = (n < 50) ? W1[(size_t)k * 50 + n] : 0.f; break;
    default: v = Wm[(size_t)k * 256 + n]; break;
  }
  ws[idx] = (__bf16)v;
}

// ------------------------------- kernel A ----------------------------------
// x_proj = facts[b] @ gru_k[:,U:3U] + bias; also persists facts bf16 A-frags.
// grid (b=128, s=8); WG does Mt in [4s, 4s+4).
__global__ __launch_bounds__(256)
void xproj_kernel(const float* __restrict__ facts,
                  const float* __restrict__ question,
                  const float* __restrict__ gru_bg,
                  bf16_t* __restrict__ ws,
                  float* __restrict__ mem_ws) {
  const int b = blockIdx.x, s = blockIdx.y;
  const int tid = threadIdx.x, w = tid >> 6, lane = tid & 63;
  const int quad = lane >> 4, col = lane & 15;
  __shared__ float grub[512];
  __shared__ bf16_t fragbuf[4096];   // swizzled: logical unit u at u^(u>>6)
  __shared__ bf16_t xrtrans[4096];   // swizzled: logical unit u at u^((u>>4)&3)
  grub[tid]       = gru_bg[256 + tid];
  grub[256 + tid] = gru_bg[512 + tid];
  if (s == 0) mem_ws[b * 256 + tid] = question[(size_t)b * 256 + tid];
  __syncthreads();

  bf16_t* xr_ws = ws + E_XR   + (size_t)b * 131072;
  bf16_t* xh_ws = ws + E_XHC  + (size_t)b * 131072;
  bf16_t* ff_ws = ws + E_FACTS + (size_t)b * 131072;
  const bf16_t* gbase = ws + E_GRUK;
  const int row = tid >> 4, cseg = tid & 15;

  // this thread's two swizzled fragbuf deposit units (constant across Mt)
  int wunit[2];
  #pragma unroll
  for (int half = 0; half < 2; ++half) {
    int u0 = cseg * 16 + half * 8;
    int kt = u0 >> 5, qk = (u0 >> 3) & 3;
    int u = kt * 64 + qk * 16 + row;
    wunit[half] = u ^ kt;
  }

  float v[16];
  { // cold load of first tile
    const float* src = facts + (((size_t)b * 512) + (s * 4) * 16 + row) * 256 + cseg * 16;
    #pragma unroll
    for (int i = 0; i < 4; ++i) {
      f32x4 t4 = ((const f32x4*)src)[i];
      v[4*i] = t4[0]; v[4*i+1] = t4[1]; v[4*i+2] = t4[2]; v[4*i+3] = t4[3];
    }
  }

  for (int mt = 0; mt < 4; ++mt) {
    const int Mt = s * 4 + mt;
    #pragma unroll
    for (int half = 0; half < 2; ++half) {
      bf16x8 pk;
      #pragma unroll
      for (int j = 0; j < 8; ++j) pk[j] = (__bf16)v[half * 8 + j];
      *(bf16x8*)&fragbuf[wunit[half] * 8] = pk;
    }
    ldsbar();  // bar1: fragbuf visible
    // prefetch next tile's facts (consumed at next iteration's top ->
    // ~full iteration of latency hiding; no vmcnt wait until then)
    float vn[16];
    if (mt < 3) {
      const float* src = facts + (((size_t)b * 512) + (Mt + 1) * 16 + row) * 256 + cseg * 16;
      #pragma unroll
      for (int i = 0; i < 4; ++i) {
        f32x4 t4 = ((const f32x4*)src)[i];
        vn[4*i] = t4[0]; vn[4*i+1] = t4[1]; vn[4*i+2] = t4[2]; vn[4*i+3] = t4[3];
      }
    }
    { // persist facts frags for scores (unswizzle -> ws holds logical layout)
      int p0 = 2 * tid, p1 = 2 * tid + 1;
      bf16x8 f0 = *(bf16x8*)&fragbuf[(p0 ^ (p0 >> 6)) * 8];
      bf16x8 f1 = *(bf16x8*)&fragbuf[(p1 ^ (p1 >> 6)) * 8];
      *(bf16x8*)(ff_ws + (size_t)Mt * 4096 + (size_t)p0 * 8) = f0;
      *(bf16x8*)(ff_ws + (size_t)Mt * 4096 + (size_t)p1 * 8) = f1;
    }
    f32x4 acc[8];
    #pragma unroll
    for (int nt = 0; nt < 8; ++nt) acc[nt] = (f32x4){0.f, 0.f, 0.f, 0.f};
    #pragma unroll
    for (int kt = 0; kt < 8; ++kt) {
      bf16x8 af = *(const bf16x8*)&fragbuf[(size_t)(((kt * 64 + lane) ^ kt)) * 8];
      #pragma unroll
      for (int nt = 0; nt < 8; ++nt) {
        bf16x8 g = *(const bf16x8*)(gbase + (((size_t)kt * 32 + (w * 8 + nt)) * 64 + lane) * 8);
        acc[nt] = mfma16(af, g, acc[nt]);
      }
    }
    #pragma unroll
    for (int nt = 0; nt < 8; ++nt) {
      int o = w * 128 + nt * 16 + col;
      float bias = grub[o];
      if (o < 256) { // xr: C-layout -> A-frag transpose via swizzled LDS
        int ktA = o >> 5, qkA = (o >> 3) & 3, j = o & 7;
        #pragma unroll
        for (int r = 0; r < 4; ++r) {
          int u = ktA * 64 + qkA * 16 + (quad * 4 + r);
          int us = u ^ ((u >> 4) & 3);
          xrtrans[us * 8 + j] = (__bf16)(acc[nt][r] + bias);
        }
      } else {       // xh: store directly in C order
        int ntx = (o >> 4) - 16;
        unsigned short s0 = f2bf(acc[nt][0] + bias), s1 = f2bf(acc[nt][1] + bias);
        unsigned short s2 = f2bf(acc[nt][2] + bias), s3 = f2bf(acc[nt][3] + bias);
        uint2 pv;
        pv.x = (unsigned)s0 | ((unsigned)s1 << 16);
        pv.y = (unsigned)s2 | ((unsigned)s3 << 16);
        *(uint2*)(xh_ws + ((size_t)Mt * 16 + ntx) * 256 + lane * 4) = pv;
      }
    }
    ldsbar();  // bar2: xrtrans visible
    { // xr store: read swizzled, write logical (ws layout unchanged for scan)
      int p0 = 2 * tid, p1 = 2 * tid + 1;
      bf16x8 f0 = *(bf16x8*)&xrtrans[(p0 ^ ((p0 >> 4) & 3)) * 8];
      bf16x8 f1 = *(bf16x8*)&xrtrans[(p1 ^ ((p1 >> 4) & 3)) * 8];
      *(bf16x8*)(xr_ws + (size_t)Mt * 4096 + (size_t)p0 * 8) = f0;
      *(bf16x8*)(xr_ws + (size_t)Mt * 4096 + (size_t)p1 * 8) = f1;
    }
    // no bar3: bar1 of next iteration orders xrtrans reads vs next writes,
    // bar2 above orders fragbuf reads vs next iteration's fragbuf writes.
    if (mt < 3) {
      #pragma unroll
      for (int i = 0; i < 16; ++i) v[i] = vn[i];
    }
  }
}

// ------------------------------- kernel B ----------------------------------
// scores[b, n] for one episode.  grid (b=128, s=8); WG does rows [64s,64s+64).
__global__ __launch_bounds__(256)
void scores_kernel(const float* __restrict__ question,
                   const float* __restrict__ b1g,
                   const float* __restrict__ W2g,
                   const float* __restrict__ b2g,
                   const bf16_t* __restrict__ ws,
                   const float* __restrict__ mem_ws,
                   float* __restrict__ scores_ws) {
  const int b = blockIdx.x, s = blockIdx.y;
  const int tid = threadIdx.x, w = tid >> 6, lane = tid & 63;
  const int quad = lane >> 4, col = lane & 15;
  __shared__ float q_lds[256], mem_lds[256], b1_lds[64], W2_lds[64], score_lds[64];
  __shared__ float b2s;
  q_lds[tid]   = question[(size_t)b * 256 + tid];
  mem_lds[tid] = mem_ws[(size_t)b * 256 + tid];
  if (tid < 64) {
    b1_lds[tid] = (tid < 50) ? b1g[tid] : 0.f;
    W2_lds[tid] = (tid < 50) ? W2g[tid] : 0.f;
  }
  if (tid == 0) b2s = b2g[0];
  __syncthreads();
  if (tid < 64) score_lds[tid] = b2s;
  __syncthreads();

  const bf16_t* ffb = ws + E_FACTS + (size_t)b * 131072 + (size_t)s * 4 * 4096;
  const bf16_t* w1b = ws + E_W1F;

  f32x4 acc[4];
  #pragma unroll
  for (int mt = 0; mt < 4; ++mt) acc[mt] = (f32x4){0.f, 0.f, 0.f, 0.f};

  #pragma unroll 2
  for (int kt = 0; kt < 8; ++kt) {
    bf16x8 wf0 = *(const bf16x8*)(w1b + (((size_t)(kt)      * 4 + w) * 64 + lane) * 8);
    bf16x8 wf1 = *(const bf16x8*)(w1b + (((size_t)(8  + kt) * 4 + w) * 64 + lane) * 8);
    bf16x8 wf2 = *(const bf16x8*)(w1b + (((size_t)(16 + kt) * 4 + w) * 64 + lane) * 8);
    bf16x8 wf3 = *(const bf16x8*)(w1b + (((size_t)(24 + kt) * 4 + w) * 64 + lane) * 8);
    const f32x4* qp = (const f32x4*)&q_lds[kt * 32 + quad * 8];
    const f32x4* mp = (const f32x4*)&mem_lds[kt * 32 + quad * 8];
    f32x4 qa = qp[0], qb = qp[1], ma = mp[0], mb = mp[1];
    float qv[8] = {qa[0],qa[1],qa[2],qa[3],qb[0],qb[1],qb[2],qb[3]};
    float mv[8] = {ma[0],ma[1],ma[2],ma[3],mb[0],mb[1],mb[2],mb[3]};
    #pragma unroll
    for (int mt = 0; mt < 4; ++mt) {
      bf16x8 f8 = *(const bf16x8*)(ffb + (size_t)mt * 4096 + (kt * 64 + lane) * 8);
      bf16x8 a0, a1, a2, a3;
      #pragma unroll
      for (int j = 0; j < 8; ++j) {
        float fu = (float)f8[j];
        a0[j] = (__bf16)(fu * qv[j]);
        a1[j] = (__bf16)(fu * mv[j]);
        a2[j] = (__bf16)fabsf(fu - qv[j]);
        a3[j] = (__bf16)fabsf(fu - mv[j]);
      }
      acc[mt] = mfma16(a0, wf0, acc[mt]);
      acc[mt] = mfma16(a1, wf1, acc[mt]);
      acc[mt] = mfma16(a2, wf2, acc[mt]);
      acc[mt] = mfma16(a3, wf3, acc[mt]);
    }
  }
  int hcol = w * 16 + col;
  float pw2 = W2_lds[hcol], pb1 = b1_lds[hcol];
  #pragma unroll
  for (int mt = 0; mt < 4; ++mt) {
    float p[4];
    #pragma unroll
    for (int r = 0; r < 4; ++r) p[r] = tanh_f(acc[mt][r] + pb1) * pw2;
    #pragma unroll
    for (int r = 0; r < 4; ++r) {
      p[r] += __shfl_xor(p[r], 1, 64);
      p[r] += __shfl_xor(p[r], 2, 64);
      p[r] += __shfl_xor(p[r], 4, 64);
      p[r] += __shfl_xor(p[r], 8, 64);
    }
    if (col == 0) {
      #pragma unroll
      for (int r = 0; r < 4; ++r)
        atomicAdd(&score_lds[mt * 16 + quad * 4 + r], p[r]);
    }
  }
  __syncthreads();
  if (tid < 64) scores_ws[(size_t)b * 512 + s * 64 + tid] = score_lds[tid];
}

// ------------------------------- kernel C ----------------------------------
// softmax + chunked-Picard attn-GRU scan (T=32, 16 chunks) + memory update.
// 128 WGs x 512 threads.  2 barriers/chunk; h lives in LDS as bf16 A-frag
// source (broadcast ds_read_b128); exact fp32 self-term in registers.
__global__ __launch_bounds__(512, 2)
void scan_kernel(const float* __restrict__ question,
                 const float* __restrict__ bmg,
                 const bf16_t* __restrict__ ws,
                 const float* __restrict__ scores_ws,
                 float* __restrict__ mem_ws,
                 float* __restrict__ out,
                 int last) {
  const int b = blockIdx.x;
  const int tid = threadIdx.x, w = tid >> 6, lane = tid & 63;
  const int quad = lane >> 4, col = lane & 15;

  __shared__ bf16_t hb_lds[512];        // bf16 h ping-pong [0,256) / [256,512)
  __shared__ float aw_lds[512], pt_lds[16];
  __shared__ float q_lds[256], mem_lds[256], bm_lds[256], red[16];
  __shared__ bf16_t fragbuf[8192];      // rh A-frags, 2 M-tiles x 4096

  if (tid < 256) {
    q_lds[tid]   = question[(size_t)b * 256 + tid];
    mem_lds[tid] = mem_ws[(size_t)b * 256 + tid];
    bm_lds[tid]  = bmg[tid];
  }
  hb_lds[tid] = (__bf16)0.f;
  // softmax over 512 scores (1/thread)
  float s0 = scores_ws[(size_t)b * 512 + tid];
  float mx = s0;
  #pragma unroll
  for (int o = 32; o > 0; o >>= 1) mx = fmaxf(mx, __shfl_xor(mx, o, 64));
  if (lane == 0) red[w] = mx;
  __syncthreads();
  float gmax = red[0];
  #pragma unroll
  for (int i = 1; i < 8; ++i) gmax = fmaxf(gmax, red[i]);
  float e0 = __expf(s0 - gmax);
  float sm = e0;
  #pragma unroll
  for (int o = 32; o > 0; o >>= 1) sm += __shfl_xor(sm, o, 64);
  if (lane == 0) red[8 + w] = sm;
  __syncthreads();
  float tot = red[8];
  #pragma unroll
  for (int i = 9; i < 16; ++i) tot += red[i];
  aw_lds[tid] = e0 * fast_rcp(tot);
  ldsbar();
  // per-chunk (T=32) blend weights in place:
  // aw[s] := a_s * prod_{j>s in chunk}(1-a_j),  pt[ct] := prod(1-a) over chunk
  if (tid < 16) {
    float av[32];
    #pragma unroll
    for (int j = 0; j < 32; ++j) av[j] = aw_lds[tid * 32 + j];
    float suf = 1.f;
    #pragma unroll
    for (int j = 31; j >= 0; --j) {
      aw_lds[tid * 32 + j] = av[j] * suf;
      suf *= (1.f - av[j]);
    }
    pt_lds[tid] = suf;
  }
  ldsbar();

  // recurrence weight fragments: wave w owns out cols [32w, 32w+32)
  const bf16_t* xrb = ws + E_XR  + (size_t)b * 131072;
  const bf16_t* xhb = ws + E_XHC + (size_t)b * 131072;
  bf16x8 fr[2][8], fh[2][8];
  {
    const bf16_t* rb = ws + E_RKR;
    const bf16_t* hbw = ws + E_RKH;
    #pragma unroll
    for (int nt = 0; nt < 2; ++nt)
      #pragma unroll
      for (int kt = 0; kt < 8; ++kt) {
        size_t off = (((size_t)kt * 16 + (w * 2 + nt)) * 64 + lane) * 8;
        fr[nt][kt] = *(const bf16x8*)(rb + off);
        fh[nt][kt] = *(const bf16x8*)(hbw + off);
      }
  }
  // chunk-0 xr (A-frag, kt=w, 2 M-tiles) and xh (C order, 2 nt x 2 Mt)
  bf16x8 xf_c[2];
  bf16x4 xh_c[2][2];
  #pragma unroll
  for (int mt = 0; mt < 2; ++mt) {
    xf_c[mt] = *(const bf16x8*)(xrb + (size_t)mt * 4096 + ((size_t)w * 64 + lane) * 8);
    #pragma unroll
    for (int nt = 0; nt < 2; ++nt)
      xh_c[mt][nt] = *(const bf16x4*)(xhb + ((size_t)mt * 16 + w * 2 + nt) * 256 + lane * 4);
  }

  bf16_t* hbc = &hb_lds[0];
  bf16_t* hbn = &hb_lds[256];
  float hs0 = 0.f, hs1 = 0.f;  // exact fp32 self-copy of wave's own h cols

  for (int ct = 0; ct < 16; ++ct) {
    // S1: rv0 = h @ rkr.  h read as bf16 A-frag via broadcast ds_read_b128.
    // Split-K: 2 chains of 4 per acc.
    f32x4 z = (f32x4){0.f,0.f,0.f,0.f};
    f32x4 a0a = z, a0b = z, a1a = z, a1b = z;
    #pragma unroll
    for (int kt = 0; kt < 4; ++kt) {
      bf16x8 hf = *(const bf16x8*)&hbc[kt * 32 + quad * 8];
      a0a = mfma16(hf, fr[0][kt], a0a);
      a1a = mfma16(hf, fr[1][kt], a1a);
    }
    #pragma unroll
    for (int kt = 4; kt < 8; ++kt) {
      bf16x8 hf = *(const bf16x8*)&hbc[kt * 32 + quad * 8];
      a0b = mfma16(hf, fr[0][kt], a0b);
      a1b = mfma16(hf, fr[1][kt], a1b);
    }
    f32x4 ac0 = a0a + a0b, ac1 = a1a + a1b;
    // rv via intra-wave shuffles (producing wave == consuming wave):
    float rv[8];
    #pragma unroll
    for (int j = 0; j < 8; ++j) {
      int c = quad * 8 + j;
      float v0 = __shfl(ac0[0], c & 15, 64);
      float v1 = __shfl(ac1[0], c & 15, 64);
      rv[j] = (c < 16) ? v0 : v1;
    }
    // S2: rh A-frags (kt=w) for both M-tiles
    {
      bf16x8 aW = *(const bf16x8*)&hbc[w * 32 + quad * 8];
      #pragma unroll
      for (int mt = 0; mt < 2; ++mt) {
        bf16x8 rh;
        #pragma unroll
        for (int j = 0; j < 8; ++j)
          rh[j] = (__bf16)(sigmoid_f((float)xf_c[mt][j] + rv[j]) * (float)aW[j]);
        *(bf16x8*)&fragbuf[mt * 4096 + (w * 64 + lane) * 8] = rh;
      }
    }
    ldsbar();  // barrier 1: fragbuf visible
    // prefetch next chunk's xr/xh (distance 1; consumed next iteration)
    bf16x8 xf_n[2];
    bf16x4 xh_n[2][2];
    {
      int ctn = (ct + 1) & 15;
      #pragma unroll
      for (int mt = 0; mt < 2; ++mt) {
        xf_n[mt] = *(const bf16x8*)(xrb + (size_t)(2 * ctn + mt) * 4096 + ((size_t)w * 64 + lane) * 8);
        #pragma unroll
        for (int nt = 0; nt < 2; ++nt)
          xh_n[mt][nt] = *(const bf16x4*)(xhb + ((size_t)(2 * ctn + mt) * 16 + w * 2 + nt) * 256 + lane * 4);
      }
    }
    // S3: HH = rh @ rkh  (2 Mt x 2 nt = 4 independent chains of 8)
    f32x4 aH[2][2];
    #pragma unroll
    for (int mt = 0; mt < 2; ++mt) { aH[mt][0] = z; aH[mt][1] = z; }
    #pragma unroll
    for (int mt = 0; mt < 2; ++mt)
      #pragma unroll
      for (int kt = 0; kt < 8; ++kt) {
        bf16x8 a = *(const bf16x8*)&fragbuf[mt * 4096 + (kt * 64 + lane) * 8];
        aH[mt][0] = mfma16(a, fh[0][kt], aH[mt][0]);
        aH[mt][1] = mfma16(a, fh[1][kt], aH[mt][1]);
      }
    // blend over 32 steps: h_end = pt*h + sum_s aw[s]*tanh(xh+HH)[s]
    const float* awp = &aw_lds[ct * 32];
    f32x4 wq0 = *(const f32x4*)&awp[quad * 4];
    f32x4 wq1 = *(const f32x4*)&awp[16 + quad * 4];
    float Pt = pt_lds[ct];
    float part0 = 0.f, part1 = 0.f;
    #pragma unroll
    for (int r = 0; r < 4; ++r) {
      part0 += wq0[r] * tanh_f((float)xh_c[0][0][r] + aH[0][0][r]);
      part1 += wq0[r] * tanh_f((float)xh_c[0][1][r] + aH[0][1][r]);
      part0 += wq1[r] * tanh_f((float)xh_c[1][0][r] + aH[1][0][r]);
      part1 += wq1[r] * tanh_f((float)xh_c[1][1][r] + aH[1][1][r]);
    }
    part0 += __shfl_xor(part0, 16, 64); part0 += __shfl_xor(part0, 32, 64);
    part1 += __shfl_xor(part1, 16, 64); part1 += __shfl_xor(part1, 32, 64);
    float hn0 = Pt * hs0 + part0;
    float hn1 = Pt * hs1 + part1;
    hs0 = hn0; hs1 = hn1;
    if (quad == 0) {       // ping-pong write (bf16) — target not being read
      hbn[w * 32 + col]      = (__bf16)hn0;
      hbn[w * 32 + 16 + col] = (__bf16)hn1;
    }
    ldsbar();  // barrier 2: new h visible; fragbuf free
    { bf16_t* t = hbc; hbc = hbn; hbn = t; }
    #pragma unroll
    for (int mt = 0; mt < 2; ++mt) {
      xf_c[mt] = xf_n[mt];
      xh_c[mt][0] = xh_n[mt][0];
      xh_c[mt][1] = xh_n[mt][1];
    }
  }
  // hbc now holds the episode vector (bf16)

  // phase D: memory = relu([mem, episode, q] @ Wm + bm)
  {
    f32x4 am0 = (f32x4){0.f,0.f,0.f,0.f}, am1 = am0;
    const bf16_t* wmb = ws + E_WMF;
    #pragma unroll
    for (int kt = 0; kt < 24; ++kt) {
      bf16x8 a;
      if (kt >= 8 && kt < 16) {           // episode: already bf16, broadcast read
        a = *(const bf16x8*)&hbc[(kt - 8) * 32 + quad * 8];
      } else {
        const float* sv = (kt < 8) ? &mem_lds[kt * 32] : &q_lds[(kt - 16) * 32];
        const f32x4* vp = (const f32x4*)&sv[quad * 8];
        f32x4 va = vp[0], vb = vp[1];
        #pragma unroll
        for (int j = 0; j < 4; ++j) { a[j] = (__bf16)va[j]; a[4 + j] = (__bf16)vb[j]; }
      }
      bf16x8 b0 = *(const bf16x8*)(wmb + (((size_t)kt * 16 + w * 2)     * 64 + lane) * 8);
      bf16x8 b1 = *(const bf16x8*)(wmb + (((size_t)kt * 16 + w * 2 + 1) * 64 + lane) * 8);
      am0 = mfma16(a, b0, am0);
      am1 = mfma16(a, b1, am1);
    }
    if (quad == 0) {
      int v0 = w * 32 + col, v1 = w * 32 + 16 + col;
      float r0 = fmaxf(am0[0] + bm_lds[v0], 0.f);
      float r1 = fmaxf(am1[0] + bm_lds[v1], 0.f);
      mem_ws[(size_t)b * 256 + v0] = r0;
      mem_ws[(size_t)b * 256 + v1] = r1;
      if (last) {
        out[(size_t)b * 256 + v0] = r0;
        out[(size_t)b * 256 + v1] = r1;
      }
    }
  }
}

extern "C" void kernel_launch(void* const* d_in, const int* in_sizes, int n_in,
                              void* d_out, int out_size, void* d_ws, size_t ws_size,
                              hipStream_t stream) {
  (void)in_sizes; (void)n_in; (void)out_size; (void)ws_size;
  const float* facts    = (const float*)d_in[0];
  const float* question = (const float*)d_in[1];
  const float* W1       = (const float*)d_in[2];
  const float* b1       = (const float*)d_in[3];
  const float* W2       = (const float*)d_in[4];
  const float* b2       = (const float*)d_in[5];
  const float* gru_k    = (const float*)d_in[6];
  const float* gru_rk   = (const float*)d_in[7];
  const float* gru_b    = (const float*)d_in[8];
  const float* Wm       = (const float*)d_in[9];
  const float* bm       = (const float*)d_in[10];
  bf16_t* ws = (bf16_t*)d_ws;
  float* fws = (float*)(ws + E_END);
  float* scores_ws = fws + F_SCORES;
  float* mem_ws    = fws + F_MEM;
  float* out = (float*)d_out;

  prep_weights<<<2048, 256, 0, stream>>>(gru_k, gru_rk, W1, Wm, ws);
  xproj_kernel<<<dim3(128, 8), 256, 0, stream>>>(facts, question, gru_b, ws, mem_ws);
  for (int ep = 0; ep < 3; ++ep) {
    scores_kernel<<<dim3(128, 8), 256, 0, stream>>>(question, b1, W2, b2, ws, mem_ws, scores_ws);
    scan_kernel<<<128, 512, 0, stream>>>(question, bm, ws, scores_ws, mem_ws, out, ep == 2);
  }
}

// Round 7
// 440.592 us; speedup vs baseline: 1.0766x; 1.0766x over previous
//
#include <hip/hip_runtime.h>
#include <cstdint>
#include <cstddef>

// ---------------------------------------------------------------------------
// Episodic memory module (DMN) on MI355X — round 7.
//
// R6 post-mortem: FAILED (xproj 71->127us).  Bank-conflict fix verified by
// counter (2.62M->0.39M) but conflicts were only ~4us of 71; the restructure
// (conditional prefetch, in-loop A-frag reads, barrier removal) halved every
// rate counter.  Revised model: xproj is bound by the gru_k B-fragment L2
// stream — 1 GB of L2 reads of the same 512KB matrix (64KB/wave/Mt).
//
// R7 (xproj only; scores/scan/prep identical):
//  * revert to R5 control flow (facts loads at loop top, straight-line body)
//  * Mt-PAIRS: one gk fragment load feeds 2 MFMAs (2 A-tiles) -> gk L2
//    traffic halved (0.5 GB), 2x arithmetic intensity on the L2 stream
//  * keep fragbuf u^=kt swizzle (16-way->none) and xrtrans u^=((u>>4)&3)
//    (8->4-way) — both verified by SQ_LDS_BANK_CONFLICT
//  * 2 barriers per pair-iteration
// ---------------------------------------------------------------------------

typedef __bf16 bf16_t;
typedef __attribute__((ext_vector_type(8))) __bf16 bf16x8;
typedef __attribute__((ext_vector_type(4))) __bf16 bf16x4;
typedef __attribute__((ext_vector_type(4))) float f32x4;

static __device__ __forceinline__ f32x4 mfma16(bf16x8 a, bf16x8 b, f32x4 c) {
  return __builtin_amdgcn_mfma_f32_16x16x32_bf16(a, b, c, 0, 0, 0);
}
static __device__ __forceinline__ float fast_rcp(float x) { return __builtin_amdgcn_rcpf(x); }
static __device__ __forceinline__ float sigmoid_f(float x) {
  return fast_rcp(1.f + exp2f(-1.44269504f * x));
}
static __device__ __forceinline__ float tanh_f(float x) {
  float e = exp2f(2.88539008f * x);
  return 1.f - 2.f * fast_rcp(e + 1.f);
}
static __device__ __forceinline__ unsigned short f2bf(float x) {
  __bf16 h = (__bf16)x;
  return __builtin_bit_cast(unsigned short, h);
}
// Workgroup barrier WITHOUT the vmcnt(0) drain __syncthreads() carries.
// All call sites are in wave-uniform control flow.
static __device__ __forceinline__ void ldsbar() {
  asm volatile("s_waitcnt lgkmcnt(0)\n\ts_barrier" ::: "memory");
}

// ws layout (bf16 element offsets).  B-fragment layout for a K x N matrix:
// elem(k,n) at ((kt*NT + nt)*64 + lane)*8 + j, kt=k/32, nt=n/16,
// lane=((k%32)/8)*16 + (n%16), j=k%8.
static constexpr size_t E_GRUK  = 0;                            // K=256 N=512
static constexpr size_t E_RKR   = 131072;                       // K=256 N=256
static constexpr size_t E_RKH   = 196608;
static constexpr size_t E_W1F   = 262144;                       // K=1024 N=64
static constexpr size_t E_WMF   = 327680;                       // K=768 N=256
static constexpr size_t E_XR    = 524288;                       // + b*131072 (A-frag)
static constexpr size_t E_XHC   = E_XR  + (size_t)128 * 131072; // + b*131072 (C order)
static constexpr size_t E_FACTS = E_XHC + (size_t)128 * 131072; // + b*131072 (A-frag)
static constexpr size_t E_END   = E_FACTS + (size_t)128 * 131072;
static constexpr size_t F_SCORES = 0;
static constexpr size_t F_MEM    = 65536;

__global__ void prep_weights(const float* __restrict__ gru_k,
                             const float* __restrict__ gru_rk,
                             const float* __restrict__ W1,
                             const float* __restrict__ Wm,
                             bf16_t* __restrict__ ws) {
  size_t idx = (size_t)blockIdx.x * 256 + threadIdx.x;
  if (idx >= 524288) return;
  size_t local; int NT, which;
  if (idx < 131072)      { local = idx;          NT = 32; which = 0; }
  else if (idx < 196608) { local = idx - 131072; NT = 16; which = 1; }
  else if (idx < 262144) { local = idx - 196608; NT = 16; which = 2; }
  else if (idx < 327680) { local = idx - 262144; NT = 4;  which = 3; }
  else                   { local = idx - 327680; NT = 16; which = 4; }
  int j    = (int)(local & 7);
  int lane = (int)((local >> 3) & 63);
  size_t rem = local >> 9;
  int nt = (int)(rem % NT);
  int kt = (int)(rem / NT);
  int k = kt * 32 + (lane >> 4) * 8 + j;
  int n = nt * 16 + (lane & 15);
  float v;
  switch (which) {
    case 0:  v = gru_k[(size_t)k * 768 + 256 + n]; break;
    case 1:  v = gru_rk[(size_t)k * 768 + 256 + n]; break;
    case 2:  v = gru_rk[(size_t)k * 768 + 512 + n]; break;
    case 3:  v = (n < 50) ? W1[(size_t)k * 50 + n] : 0.f; break;
    default: v = Wm[(size_t)k * 256 + n]; break;
  }
  ws[idx] = (__bf16)v;
}

// ------------------------------- kernel A ----------------------------------
// x_proj = facts[b] @ gru_k[:,U:3U] + bias; also persists facts bf16 A-frags.
// grid (b=128, s=8); WG does 2 pair-iterations covering Mt in [4s, 4s+4).
__global__ __launch_bounds__(256)
void xproj_kernel(const float* __restrict__ facts,
                  const float* __restrict__ question,
                  const float* __restrict__ gru_bg,
                  bf16_t* __restrict__ ws,
                  float* __restrict__ mem_ws) {
  const int b = blockIdx.x, s = blockIdx.y;
  const int tid = threadIdx.x, w = tid >> 6, lane = tid & 63;
  const int quad = lane >> 4, col = lane & 15;
  __shared__ float grub[512];
  __shared__ bf16_t fragbuf[8192];   // 2 tiles; logical unit u at u^( (u>>6) )
  __shared__ bf16_t xrtrans[8192];   // 2 tiles; logical unit u at u^((u>>4)&3)
  grub[tid]       = gru_bg[256 + tid];
  grub[256 + tid] = gru_bg[512 + tid];
  if (s == 0) mem_ws[b * 256 + tid] = question[(size_t)b * 256 + tid];
  __syncthreads();

  bf16_t* xr_ws = ws + E_XR   + (size_t)b * 131072;
  bf16_t* xh_ws = ws + E_XHC  + (size_t)b * 131072;
  bf16_t* ff_ws = ws + E_FACTS + (size_t)b * 131072;
  const bf16_t* gbase = ws + E_GRUK;
  const int row = tid >> 4, cseg = tid & 15;

  // this thread's two swizzled fragbuf deposit units (constant across tiles)
  int wunit[2];
  #pragma unroll
  for (int half = 0; half < 2; ++half) {
    int u0 = cseg * 16 + half * 8;
    int kt = u0 >> 5, qk = (u0 >> 3) & 3;
    int u = kt * 64 + qk * 16 + row;
    wunit[half] = u ^ kt;
  }

  for (int it = 0; it < 2; ++it) {
    const int Mt0 = s * 4 + 2 * it;
    // load both tiles' facts rows (consumed immediately, R5-style)
    float v[2][16];
    #pragma unroll
    for (int t = 0; t < 2; ++t) {
      const float* src = facts + (((size_t)b * 512) + (Mt0 + t) * 16 + row) * 256 + cseg * 16;
      #pragma unroll
      for (int i = 0; i < 4; ++i) {
        f32x4 t4 = ((const f32x4*)src)[i];
        v[t][4*i] = t4[0]; v[t][4*i+1] = t4[1]; v[t][4*i+2] = t4[2]; v[t][4*i+3] = t4[3];
      }
    }
    #pragma unroll
    for (int t = 0; t < 2; ++t)
      #pragma unroll
      for (int half = 0; half < 2; ++half) {
        bf16x8 pk;
        #pragma unroll
        for (int j = 0; j < 8; ++j) pk[j] = (__bf16)v[t][half * 8 + j];
        *(bf16x8*)&fragbuf[(t * 512 + wunit[half]) * 8] = pk;
      }
    ldsbar();  // bar1: fragbuf visible
    { // persist facts frags for scores (unswizzle -> ws holds logical layout)
      int p0 = 2 * tid, p1 = 2 * tid + 1;
      int q0 = p0 ^ (p0 >> 6), q1 = p1 ^ (p1 >> 6);
      #pragma unroll
      for (int t = 0; t < 2; ++t) {
        bf16x8 f0 = *(bf16x8*)&fragbuf[(t * 512 + q0) * 8];
        bf16x8 f1 = *(bf16x8*)&fragbuf[(t * 512 + q1) * 8];
        *(bf16x8*)(ff_ws + (size_t)(Mt0 + t) * 4096 + (size_t)p0 * 8) = f0;
        *(bf16x8*)(ff_ws + (size_t)(Mt0 + t) * 4096 + (size_t)p1 * 8) = f1;
      }
    }
    // paired MFMA: each gk fragment load feeds BOTH A-tiles
    f32x4 acc[2][8];
    #pragma unroll
    for (int t = 0; t < 2; ++t)
      #pragma unroll
      for (int nt = 0; nt < 8; ++nt) acc[t][nt] = (f32x4){0.f, 0.f, 0.f, 0.f};
    #pragma unroll
    for (int kt = 0; kt < 8; ++kt) {
      int us = (kt * 64 + lane) ^ kt;
      bf16x8 af0 = *(const bf16x8*)&fragbuf[(size_t)us * 8];
      bf16x8 af1 = *(const bf16x8*)&fragbuf[(size_t)(512 + us) * 8];
      #pragma unroll
      for (int nt = 0; nt < 8; ++nt) {
        bf16x8 g = *(const bf16x8*)(gbase + (((size_t)kt * 32 + (w * 8 + nt)) * 64 + lane) * 8);
        acc[0][nt] = mfma16(af0, g, acc[0][nt]);
        acc[1][nt] = mfma16(af1, g, acc[1][nt]);
      }
    }
    #pragma unroll
    for (int t = 0; t < 2; ++t)
      #pragma unroll
      for (int nt = 0; nt < 8; ++nt) {
        int o = w * 128 + nt * 16 + col;
        float bias = grub[o];
        if (o < 256) { // xr: C-layout -> A-frag transpose via swizzled LDS
          int ktA = o >> 5, qkA = (o >> 3) & 3, j = o & 7;
          #pragma unroll
          for (int r = 0; r < 4; ++r) {
            int u = ktA * 64 + qkA * 16 + (quad * 4 + r);
            int us = u ^ ((u >> 4) & 3);
            xrtrans[(t * 512 + us) * 8 + j] = (__bf16)(acc[t][nt][r] + bias);
          }
        } else {       // xh: store directly in C order
          int ntx = (o >> 4) - 16;
          unsigned short s0 = f2bf(acc[t][nt][0] + bias), s1 = f2bf(acc[t][nt][1] + bias);
          unsigned short s2 = f2bf(acc[t][nt][2] + bias), s3 = f2bf(acc[t][nt][3] + bias);
          uint2 pv;
          pv.x = (unsigned)s0 | ((unsigned)s1 << 16);
          pv.y = (unsigned)s2 | ((unsigned)s3 << 16);
          *(uint2*)(xh_ws + ((size_t)(Mt0 + t) * 16 + ntx) * 256 + lane * 4) = pv;
        }
      }
    ldsbar();  // bar2: xrtrans visible
    { // xr store: read swizzled, write logical (ws layout unchanged for scan)
      int p0 = 2 * tid, p1 = 2 * tid + 1;
      int q0 = p0 ^ ((p0 >> 4) & 3), q1 = p1 ^ ((p1 >> 4) & 3);
      #pragma unroll
      for (int t = 0; t < 2; ++t) {
        bf16x8 f0 = *(bf16x8*)&xrtrans[(t * 512 + q0) * 8];
        bf16x8 f1 = *(bf16x8*)&xrtrans[(t * 512 + q1) * 8];
        *(bf16x8*)(xr_ws + (size_t)(Mt0 + t) * 4096 + (size_t)p0 * 8) = f0;
        *(bf16x8*)(xr_ws + (size_t)(Mt0 + t) * 4096 + (size_t)p1 * 8) = f1;
      }
    }
    // no bar3: next iteration's bar1 orders xrtrans reads vs next writes
    // (each wave drains its ds_reads via lgkmcnt(0) before its s_barrier),
    // and fragbuf deposits after bar2 are safe (all frag reads were pre-bar2).
  }
}

// ------------------------------- kernel B ----------------------------------
// scores[b, n] for one episode.  grid (b=128, s=8); WG does rows [64s,64s+64).
__global__ __launch_bounds__(256)
void scores_kernel(const float* __restrict__ question,
                   const float* __restrict__ b1g,
                   const float* __restrict__ W2g,
                   const float* __restrict__ b2g,
                   const bf16_t* __restrict__ ws,
                   const float* __restrict__ mem_ws,
                   float* __restrict__ scores_ws) {
  const int b = blockIdx.x, s = blockIdx.y;
  const int tid = threadIdx.x, w = tid >> 6, lane = tid & 63;
  const int quad = lane >> 4, col = lane & 15;
  __shared__ float q_lds[256], mem_lds[256], b1_lds[64], W2_lds[64], score_lds[64];
  __shared__ float b2s;
  q_lds[tid]   = question[(size_t)b * 256 + tid];
  mem_lds[tid] = mem_ws[(size_t)b * 256 + tid];
  if (tid < 64) {
    b1_lds[tid] = (tid < 50) ? b1g[tid] : 0.f;
    W2_lds[tid] = (tid < 50) ? W2g[tid] : 0.f;
  }
  if (tid == 0) b2s = b2g[0];
  __syncthreads();
  if (tid < 64) score_lds[tid] = b2s;
  __syncthreads();

  const bf16_t* ffb = ws + E_FACTS + (size_t)b * 131072 + (size_t)s * 4 * 4096;
  const bf16_t* w1b = ws + E_W1F;

  f32x4 acc[4];
  #pragma unroll
  for (int mt = 0; mt < 4; ++mt) acc[mt] = (f32x4){0.f, 0.f, 0.f, 0.f};

  #pragma unroll 2
  for (int kt = 0; kt < 8; ++kt) {
    bf16x8 wf0 = *(const bf16x8*)(w1b + (((size_t)(kt)      * 4 + w) * 64 + lane) * 8);
    bf16x8 wf1 = *(const bf16x8*)(w1b + (((size_t)(8  + kt) * 4 + w) * 64 + lane) * 8);
    bf16x8 wf2 = *(const bf16x8*)(w1b + (((size_t)(16 + kt) * 4 + w) * 64 + lane) * 8);
    bf16x8 wf3 = *(const bf16x8*)(w1b + (((size_t)(24 + kt) * 4 + w) * 64 + lane) * 8);
    const f32x4* qp = (const f32x4*)&q_lds[kt * 32 + quad * 8];
    const f32x4* mp = (const f32x4*)&mem_lds[kt * 32 + quad * 8];
    f32x4 qa = qp[0], qb = qp[1], ma = mp[0], mb = mp[1];
    float qv[8] = {qa[0],qa[1],qa[2],qa[3],qb[0],qb[1],qb[2],qb[3]};
    float mv[8] = {ma[0],ma[1],ma[2],ma[3],mb[0],mb[1],mb[2],mb[3]};
    #pragma unroll
    for (int mt = 0; mt < 4; ++mt) {
      bf16x8 f8 = *(const bf16x8*)(ffb + (size_t)mt * 4096 + (kt * 64 + lane) * 8);
      bf16x8 a0, a1, a2, a3;
      #pragma unroll
      for (int j = 0; j < 8; ++j) {
        float fu = (float)f8[j];
        a0[j] = (__bf16)(fu * qv[j]);
        a1[j] = (__bf16)(fu * mv[j]);
        a2[j] = (__bf16)fabsf(fu - qv[j]);
        a3[j] = (__bf16)fabsf(fu - mv[j]);
      }
      acc[mt] = mfma16(a0, wf0, acc[mt]);
      acc[mt] = mfma16(a1, wf1, acc[mt]);
      acc[mt] = mfma16(a2, wf2, acc[mt]);
      acc[mt] = mfma16(a3, wf3, acc[mt]);
    }
  }
  int hcol = w * 16 + col;
  float pw2 = W2_lds[hcol], pb1 = b1_lds[hcol];
  #pragma unroll
  for (int mt = 0; mt < 4; ++mt) {
    float p[4];
    #pragma unroll
    for (int r = 0; r < 4; ++r) p[r] = tanh_f(acc[mt][r] + pb1) * pw2;
    #pragma unroll
    for (int r = 0; r < 4; ++r) {
      p[r] += __shfl_xor(p[r], 1, 64);
      p[r] += __shfl_xor(p[r], 2, 64);
      p[r] += __shfl_xor(p[r], 4, 64);
      p[r] += __shfl_xor(p[r], 8, 64);
    }
    if (col == 0) {
      #pragma unroll
      for (int r = 0; r < 4; ++r)
        atomicAdd(&score_lds[mt * 16 + quad * 4 + r], p[r]);
    }
  }
  __syncthreads();
  if (tid < 64) scores_ws[(size_t)b * 512 + s * 64 + tid] = score_lds[tid];
}

// ------------------------------- kernel C ----------------------------------
// softmax + chunked-Picard attn-GRU scan (T=32, 16 chunks) + memory update.
// 128 WGs x 512 threads.  2 barriers/chunk; h lives in LDS as bf16 A-frag
// source (broadcast ds_read_b128); exact fp32 self-term in registers.
__global__ __launch_bounds__(512, 2)
void scan_kernel(const float* __restrict__ question,
                 const float* __restrict__ bmg,
                 const bf16_t* __restrict__ ws,
                 const float* __restrict__ scores_ws,
                 float* __restrict__ mem_ws,
                 float* __restrict__ out,
                 int last) {
  const int b = blockIdx.x;
  const int tid = threadIdx.x, w = tid >> 6, lane = tid & 63;
  const int quad = lane >> 4, col = lane & 15;

  __shared__ bf16_t hb_lds[512];        // bf16 h ping-pong [0,256) / [256,512)
  __shared__ float aw_lds[512], pt_lds[16];
  __shared__ float q_lds[256], mem_lds[256], bm_lds[256], red[16];
  __shared__ bf16_t fragbuf[8192];      // rh A-frags, 2 M-tiles x 4096

  if (tid < 256) {
    q_lds[tid]   = question[(size_t)b * 256 + tid];
    mem_lds[tid] = mem_ws[(size_t)b * 256 + tid];
    bm_lds[tid]  = bmg[tid];
  }
  hb_lds[tid] = (__bf16)0.f;
  // softmax over 512 scores (1/thread)
  float s0 = scores_ws[(size_t)b * 512 + tid];
  float mx = s0;
  #pragma unroll
  for (int o = 32; o > 0; o >>= 1) mx = fmaxf(mx, __shfl_xor(mx, o, 64));
  if (lane == 0) red[w] = mx;
  __syncthreads();
  float gmax = red[0];
  #pragma unroll
  for (int i = 1; i < 8; ++i) gmax = fmaxf(gmax, red[i]);
  float e0 = __expf(s0 - gmax);
  float sm = e0;
  #pragma unroll
  for (int o = 32; o > 0; o >>= 1) sm += __shfl_xor(sm, o, 64);
  if (lane == 0) red[8 + w] = sm;
  __syncthreads();
  float tot = red[8];
  #pragma unroll
  for (int i = 9; i < 16; ++i) tot += red[i];
  aw_lds[tid] = e0 * fast_rcp(tot);
  ldsbar();
  // per-chunk (T=32) blend weights in place:
  // aw[s] := a_s * prod_{j>s in chunk}(1-a_j),  pt[ct] := prod(1-a) over chunk
  if (tid < 16) {
    float av[32];
    #pragma unroll
    for (int j = 0; j < 32; ++j) av[j] = aw_lds[tid * 32 + j];
    float suf = 1.f;
    #pragma unroll
    for (int j = 31; j >= 0; --j) {
      aw_lds[tid * 32 + j] = av[j] * suf;
      suf *= (1.f - av[j]);
    }
    pt_lds[tid] = suf;
  }
  ldsbar();

  // recurrence weight fragments: wave w owns out cols [32w, 32w+32)
  const bf16_t* xrb = ws + E_XR  + (size_t)b * 131072;
  const bf16_t* xhb = ws + E_XHC + (size_t)b * 131072;
  bf16x8 fr[2][8], fh[2][8];
  {
    const bf16_t* rb = ws + E_RKR;
    const bf16_t* hbw = ws + E_RKH;
    #pragma unroll
    for (int nt = 0; nt < 2; ++nt)
      #pragma unroll
      for (int kt = 0; kt < 8; ++kt) {
        size_t off = (((size_t)kt * 16 + (w * 2 + nt)) * 64 + lane) * 8;
        fr[nt][kt] = *(const bf16x8*)(rb + off);
        fh[nt][kt] = *(const bf16x8*)(hbw + off);
      }
  }
  // chunk-0 xr (A-frag, kt=w, 2 M-tiles) and xh (C order, 2 nt x 2 Mt)
  bf16x8 xf_c[2];
  bf16x4 xh_c[2][2];
  #pragma unroll
  for (int mt = 0; mt < 2; ++mt) {
    xf_c[mt] = *(const bf16x8*)(xrb + (size_t)mt * 4096 + ((size_t)w * 64 + lane) * 8);
    #pragma unroll
    for (int nt = 0; nt < 2; ++nt)
      xh_c[mt][nt] = *(const bf16x4*)(xhb + ((size_t)mt * 16 + w * 2 + nt) * 256 + lane * 4);
  }

  bf16_t* hbc = &hb_lds[0];
  bf16_t* hbn = &hb_lds[256];
  float hs0 = 0.f, hs1 = 0.f;  // exact fp32 self-copy of wave's own h cols

  for (int ct = 0; ct < 16; ++ct) {
    // S1: rv0 = h @ rkr.  h read as bf16 A-frag via broadcast ds_read_b128.
    // Split-K: 2 chains of 4 per acc.
    f32x4 z = (f32x4){0.f,0.f,0.f,0.f};
    f32x4 a0a = z, a0b = z, a1a = z, a1b = z;
    #pragma unroll
    for (int kt = 0; kt < 4; ++kt) {
      bf16x8 hf = *(const bf16x8*)&hbc[kt * 32 + quad * 8];
      a0a = mfma16(hf, fr[0][kt], a0a);
      a1a = mfma16(hf, fr[1][kt], a1a);
    }
    #pragma unroll
    for (int kt = 4; kt < 8; ++kt) {
      bf16x8 hf = *(const bf16x8*)&hbc[kt * 32 + quad * 8];
      a0b = mfma16(hf, fr[0][kt], a0b);
      a1b = mfma16(hf, fr[1][kt], a1b);
    }
    f32x4 ac0 = a0a + a0b, ac1 = a1a + a1b;
    // rv via intra-wave shuffles (producing wave == consuming wave):
    float rv[8];
    #pragma unroll
    for (int j = 0; j < 8; ++j) {
      int c = quad * 8 + j;
      float v0 = __shfl(ac0[0], c & 15, 64);
      float v1 = __shfl(ac1[0], c & 15, 64);
      rv[j] = (c < 16) ? v0 : v1;
    }
    // S2: rh A-frags (kt=w) for both M-tiles
    {
      bf16x8 aW = *(const bf16x8*)&hbc[w * 32 + quad * 8];
      #pragma unroll
      for (int mt = 0; mt < 2; ++mt) {
        bf16x8 rh;
        #pragma unroll
        for (int j = 0; j < 8; ++j)
          rh[j] = (__bf16)(sigmoid_f((float)xf_c[mt][j] + rv[j]) * (float)aW[j]);
        *(bf16x8*)&fragbuf[mt * 4096 + (w * 64 + lane) * 8] = rh;
      }
    }
    ldsbar();  // barrier 1: fragbuf visible
    // prefetch next chunk's xr/xh (distance 1; consumed next iteration)
    bf16x8 xf_n[2];
    bf16x4 xh_n[2][2];
    {
      int ctn = (ct + 1) & 15;
      #pragma unroll
      for (int mt = 0; mt < 2; ++mt) {
        xf_n[mt] = *(const bf16x8*)(xrb + (size_t)(2 * ctn + mt) * 4096 + ((size_t)w * 64 + lane) * 8);
        #pragma unroll
        for (int nt = 0; nt < 2; ++nt)
          xh_n[mt][nt] = *(const bf16x4*)(xhb + ((size_t)(2 * ctn + mt) * 16 + w * 2 + nt) * 256 + lane * 4);
      }
    }
    // S3: HH = rh @ rkh  (2 Mt x 2 nt = 4 independent chains of 8)
    f32x4 aH[2][2];
    #pragma unroll
    for (int mt = 0; mt < 2; ++mt) { aH[mt][0] = z; aH[mt][1] = z; }
    #pragma unroll
    for (int mt = 0; mt < 2; ++mt)
      #pragma unroll
      for (int kt = 0; kt < 8; ++kt) {
        bf16x8 a = *(const bf16x8*)&fragbuf[mt * 4096 + (kt * 64 + lane) * 8];
        aH[mt][0] = mfma16(a, fh[0][kt], aH[mt][0]);
        aH[mt][1] = mfma16(a, fh[1][kt], aH[mt][1]);
      }
    // blend over 32 steps: h_end = pt*h + sum_s aw[s]*tanh(xh+HH)[s]
    const float* awp = &aw_lds[ct * 32];
    f32x4 wq0 = *(const f32x4*)&awp[quad * 4];
    f32x4 wq1 = *(const f32x4*)&awp[16 + quad * 4];
    float Pt = pt_lds[ct];
    float part0 = 0.f, part1 = 0.f;
    #pragma unroll
    for (int r = 0; r < 4; ++r) {
      part0 += wq0[r] * tanh_f((float)xh_c[0][0][r] + aH[0][0][r]);
      part1 += wq0[r] * tanh_f((float)xh_c[0][1][r] + aH[0][1][r]);
      part0 += wq1[r] * tanh_f((float)xh_c[1][0][r] + aH[1][0][r]);
      part1 += wq1[r] * tanh_f((float)xh_c[1][1][r] + aH[1][1][r]);
    }
    part0 += __shfl_xor(part0, 16, 64); part0 += __shfl_xor(part0, 32, 64);
    part1 += __shfl_xor(part1, 16, 64); part1 += __shfl_xor(part1, 32, 64);
    float hn0 = Pt * hs0 + part0;
    float hn1 = Pt * hs1 + part1;
    hs0 = hn0; hs1 = hn1;
    if (quad == 0) {       // ping-pong write (bf16) — target not being read
      hbn[w * 32 + col]      = (__bf16)hn0;
      hbn[w * 32 + 16 + col] = (__bf16)hn1;
    }
    ldsbar();  // barrier 2: new h visible; fragbuf free
    { bf16_t* t = hbc; hbc = hbn; hbn = t; }
    #pragma unroll
    for (int mt = 0; mt < 2; ++mt) {
      xf_c[mt] = xf_n[mt];
      xh_c[mt][0] = xh_n[mt][0];
      xh_c[mt][1] = xh_n[mt][1];
    }
  }
  // hbc now holds the episode vector (bf16)

  // phase D: memory = relu([mem, episode, q] @ Wm + bm)
  {
    f32x4 am0 = (f32x4){0.f,0.f,0.f,0.f}, am1 = am0;
    const bf16_t* wmb = ws + E_WMF;
    #pragma unroll
    for (int kt = 0; kt < 24; ++kt) {
      bf16x8 a;
      if (kt >= 8 && kt < 16) {           // episode: already bf16, broadcast read
        a = *(const bf16x8*)&hbc[(kt - 8) * 32 + quad * 8];
      } else {
        const float* sv = (kt < 8) ? &mem_lds[kt * 32] : &q_lds[(kt - 16) * 32];
        const f32x4* vp = (const f32x4*)&sv[quad * 8];
        f32x4 va = vp[0], vb = vp[1];
        #pragma unroll
        for (int j = 0; j < 4; ++j) { a[j] = (__bf16)va[j]; a[4 + j] = (__bf16)vb[j]; }
      }
      bf16x8 b0 = *(const bf16x8*)(wmb + (((size_t)kt * 16 + w * 2)     * 64 + lane) * 8);
      bf16x8 b1 = *(const bf16x8*)(wmb + (((size_t)kt * 16 + w * 2 + 1) * 64 + lane) * 8);
      am0 = mfma16(a, b0, am0);
      am1 = mfma16(a, b1, am1);
    }
    if (quad == 0) {
      int v0 = w * 32 + col, v1 = w * 32 + 16 + col;
      float r0 = fmaxf(am0[0] + bm_lds[v0], 0.f);
      float r1 = fmaxf(am1[0] + bm_lds[v1], 0.f);
      mem_ws[(size_t)b * 256 + v0] = r0;
      mem_ws[(size_t)b * 256 + v1] = r1;
      if (last) {
        out[(size_t)b * 256 + v0] = r0;
        out[(size_t)b * 256 + v1] = r1;
      }
    }
  }
}

extern "C" void kernel_launch(void* const* d_in, const int* in_sizes, int n_in,
                              void* d_out, int out_size, void* d_ws, size_t ws_size,
                              hipStream_t stream) {
  (void)in_sizes; (void)n_in; (void)out_size; (void)ws_size;
  const float* facts    = (const float*)d_in[0];
  const float* question = (const float*)d_in[1];
  const float* W1       = (const float*)d_in[2];
  const float* b1       = (const float*)d_in[3];
  const float* W2       = (const float*)d_in[4];
  const float* b2       = (const float*)d_in[5];
  const float* gru_k    = (const float*)d_in[6];
  const float* gru_rk   = (const float*)d_in[7];
  const float* gru_b    = (const float*)d_in[8];
  const float* Wm       = (const float*)d_in[9];
  const float* bm       = (const float*)d_in[10];
  bf16_t* ws = (bf16_t*)d_ws;
  float* fws = (float*)(ws + E_END);
  float* scores_ws = fws + F_SCORES;
  float* mem_ws    = fws + F_MEM;
  float* out = (float*)d_out;

  prep_weights<<<2048, 256, 0, stream>>>(gru_k, gru_rk, W1, Wm, ws);
  xproj_kernel<<<dim3(128, 8), 256, 0, stream>>>(facts, question, gru_b, ws, mem_ws);
  for (int ep = 0; ep < 3; ++ep) {
    scores_kernel<<<dim3(128, 8), 256, 0, stream>>>(question, b1, W2, b2, ws, mem_ws, scores_ws);
    scan_kernel<<<128, 512, 0, stream>>>(question, bm, ws, scores_ws, mem_ws, out, ep == 2);
  }
}

// Round 8
// 408.587 us; speedup vs baseline: 1.1609x; 1.0783x over previous
//
#include <hip/hip_runtime.h>
#include <cstdint>
#include <cstddef>

// ---------------------------------------------------------------------------
// Episodic memory module (DMN) on MI355X — round 8.
//
// R7 post-mortem: gk-pairing confirmed directionally (127->97 vs R6) but
// VGPR 172 halved occupancy (Occ 9.4%) and lost to R5's 71us @ Occ 19.5%.
// Occupancy is the stronger lever in this latency-bound kernel.
//
// R8 (xproj only): pairing AND occupancy.  512-thread WG (8 waves), each
// wave owns nt=4 (64 out cols) -> acc[2][4]=32 VGPRs; grid (128,8), WG does
// 4 Mt as 2 pair-iterations; gk L2 traffic 512MB (R5: 1GB) at R5 occupancy.
// __launch_bounds__(512,4) caps VGPR at 128 (4 waves/SIMD).  Epilogue
// branches are now wave-uniform (waves 0-3 xr / 4-7 xh).  Verified swizzles
// kept.  scores/scan/prep byte-identical.
// ---------------------------------------------------------------------------

typedef __bf16 bf16_t;
typedef __attribute__((ext_vector_type(8))) __bf16 bf16x8;
typedef __attribute__((ext_vector_type(4))) __bf16 bf16x4;
typedef __attribute__((ext_vector_type(4))) float f32x4;

static __device__ __forceinline__ f32x4 mfma16(bf16x8 a, bf16x8 b, f32x4 c) {
  return __builtin_amdgcn_mfma_f32_16x16x32_bf16(a, b, c, 0, 0, 0);
}
static __device__ __forceinline__ float fast_rcp(float x) { return __builtin_amdgcn_rcpf(x); }
static __device__ __forceinline__ float sigmoid_f(float x) {
  return fast_rcp(1.f + exp2f(-1.44269504f * x));
}
static __device__ __forceinline__ float tanh_f(float x) {
  float e = exp2f(2.88539008f * x);
  return 1.f - 2.f * fast_rcp(e + 1.f);
}
static __device__ __forceinline__ unsigned short f2bf(float x) {
  __bf16 h = (__bf16)x;
  return __builtin_bit_cast(unsigned short, h);
}
// Workgroup barrier WITHOUT the vmcnt(0) drain __syncthreads() carries.
// All call sites are in wave-uniform control flow.
static __device__ __forceinline__ void ldsbar() {
  asm volatile("s_waitcnt lgkmcnt(0)\n\ts_barrier" ::: "memory");
}

// ws layout (bf16 element offsets).  B-fragment layout for a K x N matrix:
// elem(k,n) at ((kt*NT + nt)*64 + lane)*8 + j, kt=k/32, nt=n/16,
// lane=((k%32)/8)*16 + (n%16), j=k%8.
static constexpr size_t E_GRUK  = 0;                            // K=256 N=512
static constexpr size_t E_RKR   = 131072;                       // K=256 N=256
static constexpr size_t E_RKH   = 196608;
static constexpr size_t E_W1F   = 262144;                       // K=1024 N=64
static constexpr size_t E_WMF   = 327680;                       // K=768 N=256
static constexpr size_t E_XR    = 524288;                       // + b*131072 (A-frag)
static constexpr size_t E_XHC   = E_XR  + (size_t)128 * 131072; // + b*131072 (C order)
static constexpr size_t E_FACTS = E_XHC + (size_t)128 * 131072; // + b*131072 (A-frag)
static constexpr size_t E_END   = E_FACTS + (size_t)128 * 131072;
static constexpr size_t F_SCORES = 0;
static constexpr size_t F_MEM    = 65536;

__global__ void prep_weights(const float* __restrict__ gru_k,
                             const float* __restrict__ gru_rk,
                             const float* __restrict__ W1,
                             const float* __restrict__ Wm,
                             bf16_t* __restrict__ ws) {
  size_t idx = (size_t)blockIdx.x * 256 + threadIdx.x;
  if (idx >= 524288) return;
  size_t local; int NT, which;
  if (idx < 131072)      { local = idx;          NT = 32; which = 0; }
  else if (idx < 196608) { local = idx - 131072; NT = 16; which = 1; }
  else if (idx < 262144) { local = idx - 196608; NT = 16; which = 2; }
  else if (idx < 327680) { local = idx - 262144; NT = 4;  which = 3; }
  else                   { local = idx - 327680; NT = 16; which = 4; }
  int j    = (int)(local & 7);
  int lane = (int)((local >> 3) & 63);
  size_t rem = local >> 9;
  int nt = (int)(rem % NT);
  int kt = (int)(rem / NT);
  int k = kt * 32 + (lane >> 4) * 8 + j;
  int n = nt * 16 + (lane & 15);
  float v;
  switch (which) {
    case 0:  v = gru_k[(size_t)k * 768 + 256 + n]; break;
    case 1:  v = gru_rk[(size_t)k * 768 + 256 + n]; break;
    case 2:  v = gru_rk[(size_t)k * 768 + 512 + n]; break;
    case 3:  v = (n < 50) ? W1[(size_t)k * 50 + n] : 0.f; break;
    default: v = Wm[(size_t)k * 256 + n]; break;
  }
  ws[idx] = (__bf16)v;
}

// ------------------------------- kernel A ----------------------------------
// x_proj = facts[b] @ gru_k[:,U:3U] + bias; also persists facts bf16 A-frags.
// grid (b=128, s=8), 512 threads (8 waves, nt=4/wave).  WG does Mt in
// [4s,4s+4) as 2 pair-iterations; each gk fragment feeds 2 A-tiles.
__global__ __launch_bounds__(512, 4)
void xproj_kernel(const float* __restrict__ facts,
                  const float* __restrict__ question,
                  const float* __restrict__ gru_bg,
                  bf16_t* __restrict__ ws,
                  float* __restrict__ mem_ws) {
  const int b = blockIdx.x, s = blockIdx.y;
  const int tid = threadIdx.x, w = tid >> 6, lane = tid & 63;
  const int quad = lane >> 4, col = lane & 15;
  __shared__ float grub[512];
  __shared__ bf16_t fragbuf[8192];   // 2 tiles; logical unit u at u^kt (swizzled)
  __shared__ bf16_t xrtrans[8192];   // 2 tiles; logical unit u at u^((u>>4)&3)
  grub[tid] = gru_bg[256 + tid];     // [0,256)=xr bias, [256,512)=xh bias
  if (s == 0 && tid < 256) mem_ws[b * 256 + tid] = question[(size_t)b * 256 + tid];
  __syncthreads();

  bf16_t* xr_ws = ws + E_XR   + (size_t)b * 131072;
  bf16_t* xh_ws = ws + E_XHC  + (size_t)b * 131072;
  bf16_t* ff_ws = ws + E_FACTS + (size_t)b * 131072;
  const bf16_t* gbase = ws + E_GRUK;
  // staging ownership: 512 threads cover 2 tiles x 16 rows x 16 col-segs
  const int tile = tid >> 8, row = (tid >> 4) & 15, cseg = tid & 15;

  // this thread's two swizzled fragbuf deposit units (constant across iters)
  int wunit[2];
  #pragma unroll
  for (int half = 0; half < 2; ++half) {
    int u0 = cseg * 16 + half * 8;
    int kt = u0 >> 5, qk = (u0 >> 3) & 3;
    int u = kt * 64 + qk * 16 + row;
    wunit[half] = tile * 512 + (u ^ kt);
  }

  for (int it = 0; it < 2; ++it) {
    const int Mt0 = s * 4 + 2 * it;
    // stage this thread's 16 facts floats (one tile each; 512 thr = 2 tiles)
    float v[16];
    {
      const float* src = facts + (((size_t)b * 512) + (Mt0 + tile) * 16 + row) * 256 + cseg * 16;
      #pragma unroll
      for (int i = 0; i < 4; ++i) {
        f32x4 t4 = ((const f32x4*)src)[i];
        v[4*i] = t4[0]; v[4*i+1] = t4[1]; v[4*i+2] = t4[2]; v[4*i+3] = t4[3];
      }
    }
    #pragma unroll
    for (int half = 0; half < 2; ++half) {
      bf16x8 pk;
      #pragma unroll
      for (int j = 0; j < 8; ++j) pk[j] = (__bf16)v[half * 8 + j];
      *(bf16x8*)&fragbuf[wunit[half] * 8] = pk;
    }
    ldsbar();  // bar1: fragbuf visible
    { // persist facts frags for scores (unswizzle -> ws holds logical layout)
      #pragma unroll
      for (int e = 0; e < 2; ++e) {
        int p = 2 * tid + e;
        int t = p >> 9, pu = p & 511;
        int qu = pu ^ (pu >> 6);
        bf16x8 f = *(bf16x8*)&fragbuf[(t * 512 + qu) * 8];
        *(bf16x8*)(ff_ws + (size_t)(Mt0 + t) * 4096 + (size_t)pu * 8) = f;
      }
    }
    // paired MFMA: each gk fragment load feeds BOTH A-tiles; wave owns nt=4
    f32x4 acc[2][4];
    #pragma unroll
    for (int t = 0; t < 2; ++t)
      #pragma unroll
      for (int nt = 0; nt < 4; ++nt) acc[t][nt] = (f32x4){0.f, 0.f, 0.f, 0.f};
    #pragma unroll
    for (int kt = 0; kt < 8; ++kt) {
      int us = (kt * 64 + lane) ^ kt;
      bf16x8 af0 = *(const bf16x8*)&fragbuf[(size_t)us * 8];
      bf16x8 af1 = *(const bf16x8*)&fragbuf[(size_t)(512 + us) * 8];
      #pragma unroll
      for (int nt = 0; nt < 4; ++nt) {
        bf16x8 g = *(const bf16x8*)(gbase + (((size_t)kt * 32 + (w * 4 + nt)) * 64 + lane) * 8);
        acc[0][nt] = mfma16(af0, g, acc[0][nt]);
        acc[1][nt] = mfma16(af1, g, acc[1][nt]);
      }
    }
    // epilogue: waves 0-3 -> xr (transpose via swizzled LDS), 4-7 -> xh
    #pragma unroll
    for (int t = 0; t < 2; ++t)
      #pragma unroll
      for (int nt = 0; nt < 4; ++nt) {
        int o = w * 64 + nt * 16 + col;
        float bias = grub[o];
        if (o < 256) { // wave-uniform: w < 4
          int ktA = o >> 5, qkA = (o >> 3) & 3, j = o & 7;
          #pragma unroll
          for (int r = 0; r < 4; ++r) {
            int u = ktA * 64 + qkA * 16 + (quad * 4 + r);
            int us2 = u ^ ((u >> 4) & 3);
            xrtrans[(t * 512 + us2) * 8 + j] = (__bf16)(acc[t][nt][r] + bias);
          }
        } else {       // wave-uniform: w >= 4
          int ntx = (o >> 4) - 16;
          unsigned short s0 = f2bf(acc[t][nt][0] + bias), s1 = f2bf(acc[t][nt][1] + bias);
          unsigned short s2 = f2bf(acc[t][nt][2] + bias), s3 = f2bf(acc[t][nt][3] + bias);
          uint2 pv;
          pv.x = (unsigned)s0 | ((unsigned)s1 << 16);
          pv.y = (unsigned)s2 | ((unsigned)s3 << 16);
          *(uint2*)(xh_ws + ((size_t)(Mt0 + t) * 16 + ntx) * 256 + lane * 4) = pv;
        }
      }
    ldsbar();  // bar2: xrtrans visible
    { // xr store: read swizzled, write logical (ws layout unchanged for scan)
      #pragma unroll
      for (int e = 0; e < 2; ++e) {
        int p = 2 * tid + e;
        int t = p >> 9, pu = p & 511;
        int qu = pu ^ ((pu >> 4) & 3);
        bf16x8 f = *(bf16x8*)&xrtrans[(t * 512 + qu) * 8];
        *(bf16x8*)(xr_ws + (size_t)(Mt0 + t) * 4096 + (size_t)pu * 8) = f;
      }
    }
    // no bar3: next iteration's bar1 orders xrtrans reads vs next writes.
  }
}

// ------------------------------- kernel B ----------------------------------
// scores[b, n] for one episode.  grid (b=128, s=8); WG does rows [64s,64s+64).
__global__ __launch_bounds__(256)
void scores_kernel(const float* __restrict__ question,
                   const float* __restrict__ b1g,
                   const float* __restrict__ W2g,
                   const float* __restrict__ b2g,
                   const bf16_t* __restrict__ ws,
                   const float* __restrict__ mem_ws,
                   float* __restrict__ scores_ws) {
  const int b = blockIdx.x, s = blockIdx.y;
  const int tid = threadIdx.x, w = tid >> 6, lane = tid & 63;
  const int quad = lane >> 4, col = lane & 15;
  __shared__ float q_lds[256], mem_lds[256], b1_lds[64], W2_lds[64], score_lds[64];
  __shared__ float b2s;
  q_lds[tid]   = question[(size_t)b * 256 + tid];
  mem_lds[tid] = mem_ws[(size_t)b * 256 + tid];
  if (tid < 64) {
    b1_lds[tid] = (tid < 50) ? b1g[tid] : 0.f;
    W2_lds[tid] = (tid < 50) ? W2g[tid] : 0.f;
  }
  if (tid == 0) b2s = b2g[0];
  __syncthreads();
  if (tid < 64) score_lds[tid] = b2s;
  __syncthreads();

  const bf16_t* ffb = ws + E_FACTS + (size_t)b * 131072 + (size_t)s * 4 * 4096;
  const bf16_t* w1b = ws + E_W1F;

  f32x4 acc[4];
  #pragma unroll
  for (int mt = 0; mt < 4; ++mt) acc[mt] = (f32x4){0.f, 0.f, 0.f, 0.f};

  #pragma unroll 2
  for (int kt = 0; kt < 8; ++kt) {
    bf16x8 wf0 = *(const bf16x8*)(w1b + (((size_t)(kt)      * 4 + w) * 64 + lane) * 8);
    bf16x8 wf1 = *(const bf16x8*)(w1b + (((size_t)(8  + kt) * 4 + w) * 64 + lane) * 8);
    bf16x8 wf2 = *(const bf16x8*)(w1b + (((size_t)(16 + kt) * 4 + w) * 64 + lane) * 8);
    bf16x8 wf3 = *(const bf16x8*)(w1b + (((size_t)(24 + kt) * 4 + w) * 64 + lane) * 8);
    const f32x4* qp = (const f32x4*)&q_lds[kt * 32 + quad * 8];
    const f32x4* mp = (const f32x4*)&mem_lds[kt * 32 + quad * 8];
    f32x4 qa = qp[0], qb = qp[1], ma = mp[0], mb = mp[1];
    float qv[8] = {qa[0],qa[1],qa[2],qa[3],qb[0],qb[1],qb[2],qb[3]};
    float mv[8] = {ma[0],ma[1],ma[2],ma[3],mb[0],mb[1],mb[2],mb[3]};
    #pragma unroll
    for (int mt = 0; mt < 4; ++mt) {
      bf16x8 f8 = *(const bf16x8*)(ffb + (size_t)mt * 4096 + (kt * 64 + lane) * 8);
      bf16x8 a0, a1, a2, a3;
      #pragma unroll
      for (int j = 0; j < 8; ++j) {
        float fu = (float)f8[j];
        a0[j] = (__bf16)(fu * qv[j]);
        a1[j] = (__bf16)(fu * mv[j]);
        a2[j] = (__bf16)fabsf(fu - qv[j]);
        a3[j] = (__bf16)fabsf(fu - mv[j]);
      }
      acc[mt] = mfma16(a0, wf0, acc[mt]);
      acc[mt] = mfma16(a1, wf1, acc[mt]);
      acc[mt] = mfma16(a2, wf2, acc[mt]);
      acc[mt] = mfma16(a3, wf3, acc[mt]);
    }
  }
  int hcol = w * 16 + col;
  float pw2 = W2_lds[hcol], pb1 = b1_lds[hcol];
  #pragma unroll
  for (int mt = 0; mt < 4; ++mt) {
    float p[4];
    #pragma unroll
    for (int r = 0; r < 4; ++r) p[r] = tanh_f(acc[mt][r] + pb1) * pw2;
    #pragma unroll
    for (int r = 0; r < 4; ++r) {
      p[r] += __shfl_xor(p[r], 1, 64);
      p[r] += __shfl_xor(p[r], 2, 64);
      p[r] += __shfl_xor(p[r], 4, 64);
      p[r] += __shfl_xor(p[r], 8, 64);
    }
    if (col == 0) {
      #pragma unroll
      for (int r = 0; r < 4; ++r)
        atomicAdd(&score_lds[mt * 16 + quad * 4 + r], p[r]);
    }
  }
  __syncthreads();
  if (tid < 64) scores_ws[(size_t)b * 512 + s * 64 + tid] = score_lds[tid];
}

// ------------------------------- kernel C ----------------------------------
// softmax + chunked-Picard attn-GRU scan (T=32, 16 chunks) + memory update.
// 128 WGs x 512 threads.  2 barriers/chunk; h lives in LDS as bf16 A-frag
// source (broadcast ds_read_b128); exact fp32 self-term in registers.
__global__ __launch_bounds__(512, 2)
void scan_kernel(const float* __restrict__ question,
                 const float* __restrict__ bmg,
                 const bf16_t* __restrict__ ws,
                 const float* __restrict__ scores_ws,
                 float* __restrict__ mem_ws,
                 float* __restrict__ out,
                 int last) {
  const int b = blockIdx.x;
  const int tid = threadIdx.x, w = tid >> 6, lane = tid & 63;
  const int quad = lane >> 4, col = lane & 15;

  __shared__ bf16_t hb_lds[512];        // bf16 h ping-pong [0,256) / [256,512)
  __shared__ float aw_lds[512], pt_lds[16];
  __shared__ float q_lds[256], mem_lds[256], bm_lds[256], red[16];
  __shared__ bf16_t fragbuf[8192];      // rh A-frags, 2 M-tiles x 4096

  if (tid < 256) {
    q_lds[tid]   = question[(size_t)b * 256 + tid];
    mem_lds[tid] = mem_ws[(size_t)b * 256 + tid];
    bm_lds[tid]  = bmg[tid];
  }
  hb_lds[tid] = (__bf16)0.f;
  // softmax over 512 scores (1/thread)
  float s0 = scores_ws[(size_t)b * 512 + tid];
  float mx = s0;
  #pragma unroll
  for (int o = 32; o > 0; o >>= 1) mx = fmaxf(mx, __shfl_xor(mx, o, 64));
  if (lane == 0) red[w] = mx;
  __syncthreads();
  float gmax = red[0];
  #pragma unroll
  for (int i = 1; i < 8; ++i) gmax = fmaxf(gmax, red[i]);
  float e0 = __expf(s0 - gmax);
  float sm = e0;
  #pragma unroll
  for (int o = 32; o > 0; o >>= 1) sm += __shfl_xor(sm, o, 64);
  if (lane == 0) red[8 + w] = sm;
  __syncthreads();
  float tot = red[8];
  #pragma unroll
  for (int i = 9; i < 16; ++i) tot += red[i];
  aw_lds[tid] = e0 * fast_rcp(tot);
  ldsbar();
  // per-chunk (T=32) blend weights in place:
  // aw[s] := a_s * prod_{j>s in chunk}(1-a_j),  pt[ct] := prod(1-a) over chunk
  if (tid < 16) {
    float av[32];
    #pragma unroll
    for (int j = 0; j < 32; ++j) av[j] = aw_lds[tid * 32 + j];
    float suf = 1.f;
    #pragma unroll
    for (int j = 31; j >= 0; --j) {
      aw_lds[tid * 32 + j] = av[j] * suf;
      suf *= (1.f - av[j]);
    }
    pt_lds[tid] = suf;
  }
  ldsbar();

  // recurrence weight fragments: wave w owns out cols [32w, 32w+32)
  const bf16_t* xrb = ws + E_XR  + (size_t)b * 131072;
  const bf16_t* xhb = ws + E_XHC + (size_t)b * 131072;
  bf16x8 fr[2][8], fh[2][8];
  {
    const bf16_t* rb = ws + E_RKR;
    const bf16_t* hbw = ws + E_RKH;
    #pragma unroll
    for (int nt = 0; nt < 2; ++nt)
      #pragma unroll
      for (int kt = 0; kt < 8; ++kt) {
        size_t off = (((size_t)kt * 16 + (w * 2 + nt)) * 64 + lane) * 8;
        fr[nt][kt] = *(const bf16x8*)(rb + off);
        fh[nt][kt] = *(const bf16x8*)(hbw + off);
      }
  }
  // chunk-0 xr (A-frag, kt=w, 2 M-tiles) and xh (C order, 2 nt x 2 Mt)
  bf16x8 xf_c[2];
  bf16x4 xh_c[2][2];
  #pragma unroll
  for (int mt = 0; mt < 2; ++mt) {
    xf_c[mt] = *(const bf16x8*)(xrb + (size_t)mt * 4096 + ((size_t)w * 64 + lane) * 8);
    #pragma unroll
    for (int nt = 0; nt < 2; ++nt)
      xh_c[mt][nt] = *(const bf16x4*)(xhb + ((size_t)mt * 16 + w * 2 + nt) * 256 + lane * 4);
  }

  bf16_t* hbc = &hb_lds[0];
  bf16_t* hbn = &hb_lds[256];
  float hs0 = 0.f, hs1 = 0.f;  // exact fp32 self-copy of wave's own h cols

  for (int ct = 0; ct < 16; ++ct) {
    // S1: rv0 = h @ rkr.  h read as bf16 A-frag via broadcast ds_read_b128.
    // Split-K: 2 chains of 4 per acc.
    f32x4 z = (f32x4){0.f,0.f,0.f,0.f};
    f32x4 a0a = z, a0b = z, a1a = z, a1b = z;
    #pragma unroll
    for (int kt = 0; kt < 4; ++kt) {
      bf16x8 hf = *(const bf16x8*)&hbc[kt * 32 + quad * 8];
      a0a = mfma16(hf, fr[0][kt], a0a);
      a1a = mfma16(hf, fr[1][kt], a1a);
    }
    #pragma unroll
    for (int kt = 4; kt < 8; ++kt) {
      bf16x8 hf = *(const bf16x8*)&hbc[kt * 32 + quad * 8];
      a0b = mfma16(hf, fr[0][kt], a0b);
      a1b = mfma16(hf, fr[1][kt], a1b);
    }
    f32x4 ac0 = a0a + a0b, ac1 = a1a + a1b;
    // rv via intra-wave shuffles (producing wave == consuming wave):
    float rv[8];
    #pragma unroll
    for (int j = 0; j < 8; ++j) {
      int c = quad * 8 + j;
      float v0 = __shfl(ac0[0], c & 15, 64);
      float v1 = __shfl(ac1[0], c & 15, 64);
      rv[j] = (c < 16) ? v0 : v1;
    }
    // S2: rh A-frags (kt=w) for both M-tiles
    {
      bf16x8 aW = *(const bf16x8*)&hbc[w * 32 + quad * 8];
      #pragma unroll
      for (int mt = 0; mt < 2; ++mt) {
        bf16x8 rh;
        #pragma unroll
        for (int j = 0; j < 8; ++j)
          rh[j] = (__bf16)(sigmoid_f((float)xf_c[mt][j] + rv[j]) * (float)aW[j]);
        *(bf16x8*)&fragbuf[mt * 4096 + (w * 64 + lane) * 8] = rh;
      }
    }
    ldsbar();  // barrier 1: fragbuf visible
    // prefetch next chunk's xr/xh (distance 1; consumed next iteration)
    bf16x8 xf_n[2];
    bf16x4 xh_n[2][2];
    {
      int ctn = (ct + 1) & 15;
      #pragma unroll
      for (int mt = 0; mt < 2; ++mt) {
        xf_n[mt] = *(const bf16x8*)(xrb + (size_t)(2 * ctn + mt) * 4096 + ((size_t)w * 64 + lane) * 8);
        #pragma unroll
        for (int nt = 0; nt < 2; ++nt)
          xh_n[mt][nt] = *(const bf16x4*)(xhb + ((size_t)(2 * ctn + mt) * 16 + w * 2 + nt) * 256 + lane * 4);
      }
    }
    // S3: HH = rh @ rkh  (2 Mt x 2 nt = 4 independent chains of 8)
    f32x4 aH[2][2];
    #pragma unroll
    for (int mt = 0; mt < 2; ++mt) { aH[mt][0] = z; aH[mt][1] = z; }
    #pragma unroll
    for (int mt = 0; mt < 2; ++mt)
      #pragma unroll
      for (int kt = 0; kt < 8; ++kt) {
        bf16x8 a = *(const bf16x8*)&fragbuf[mt * 4096 + (kt * 64 + lane) * 8];
        aH[mt][0] = mfma16(a, fh[0][kt], aH[mt][0]);
        aH[mt][1] = mfma16(a, fh[1][kt], aH[mt][1]);
      }
    // blend over 32 steps: h_end = pt*h + sum_s aw[s]*tanh(xh+HH)[s]
    const float* awp = &aw_lds[ct * 32];
    f32x4 wq0 = *(const f32x4*)&awp[quad * 4];
    f32x4 wq1 = *(const f32x4*)&awp[16 + quad * 4];
    float Pt = pt_lds[ct];
    float part0 = 0.f, part1 = 0.f;
    #pragma unroll
    for (int r = 0; r < 4; ++r) {
      part0 += wq0[r] * tanh_f((float)xh_c[0][0][r] + aH[0][0][r]);
      part1 += wq0[r] * tanh_f((float)xh_c[0][1][r] + aH[0][1][r]);
      part0 += wq1[r] * tanh_f((float)xh_c[1][0][r] + aH[1][0][r]);
      part1 += wq1[r] * tanh_f((float)xh_c[1][1][r] + aH[1][1][r]);
    }
    part0 += __shfl_xor(part0, 16, 64); part0 += __shfl_xor(part0, 32, 64);
    part1 += __shfl_xor(part1, 16, 64); part1 += __shfl_xor(part1, 32, 64);
    float hn0 = Pt * hs0 + part0;
    float hn1 = Pt * hs1 + part1;
    hs0 = hn0; hs1 = hn1;
    if (quad == 0) {       // ping-pong write (bf16) — target not being read
      hbn[w * 32 + col]      = (__bf16)hn0;
      hbn[w * 32 + 16 + col] = (__bf16)hn1;
    }
    ldsbar();  // barrier 2: new h visible; fragbuf free
    { bf16_t* t = hbc; hbc = hbn; hbn = t; }
    #pragma unroll
    for (int mt = 0; mt < 2; ++mt) {
      xf_c[mt] = xf_n[mt];
      xh_c[mt][0] = xh_n[mt][0];
      xh_c[mt][1] = xh_n[mt][1];
    }
  }
  // hbc now holds the episode vector (bf16)

  // phase D: memory = relu([mem, episode, q] @ Wm + bm)
  {
    f32x4 am0 = (f32x4){0.f,0.f,0.f,0.f}, am1 = am0;
    const bf16_t* wmb = ws + E_WMF;
    #pragma unroll
    for (int kt = 0; kt < 24; ++kt) {
      bf16x8 a;
      if (kt >= 8 && kt < 16) {           // episode: already bf16, broadcast read
        a = *(const bf16x8*)&hbc[(kt - 8) * 32 + quad * 8];
      } else {
        const float* sv = (kt < 8) ? &mem_lds[kt * 32] : &q_lds[(kt - 16) * 32];
        const f32x4* vp = (const f32x4*)&sv[quad * 8];
        f32x4 va = vp[0], vb = vp[1];
        #pragma unroll
        for (int j = 0; j < 4; ++j) { a[j] = (__bf16)va[j]; a[4 + j] = (__bf16)vb[j]; }
      }
      bf16x8 b0 = *(const bf16x8*)(wmb + (((size_t)kt * 16 + w * 2)     * 64 + lane) * 8);
      bf16x8 b1 = *(const bf16x8*)(wmb + (((size_t)kt * 16 + w * 2 + 1) * 64 + lane) * 8);
      am0 = mfma16(a, b0, am0);
      am1 = mfma16(a, b1, am1);
    }
    if (quad == 0) {
      int v0 = w * 32 + col, v1 = w * 32 + 16 + col;
      float r0 = fmaxf(am0[0] + bm_lds[v0], 0.f);
      float r1 = fmaxf(am1[0] + bm_lds[v1], 0.f);
      mem_ws[(size_t)b * 256 + v0] = r0;
      mem_ws[(size_t)b * 256 + v1] = r1;
      if (last) {
        out[(size_t)b * 256 + v0] = r0;
        out[(size_t)b * 256 + v1] = r1;
      }
    }
  }
}

extern "C" void kernel_launch(void* const* d_in, const int* in_sizes, int n_in,
                              void* d_out, int out_size, void* d_ws, size_t ws_size,
                              hipStream_t stream) {
  (void)in_sizes; (void)n_in; (void)out_size; (void)ws_size;
  const float* facts    = (const float*)d_in[0];
  const float* question = (const float*)d_in[1];
  const float* W1       = (const float*)d_in[2];
  const float* b1       = (const float*)d_in[3];
  const float* W2       = (const float*)d_in[4];
  const float* b2       = (const float*)d_in[5];
  const float* gru_k    = (const float*)d_in[6];
  const float* gru_rk   = (const float*)d_in[7];
  const float* gru_b    = (const float*)d_in[8];
  const float* Wm       = (const float*)d_in[9];
  const float* bm       = (const float*)d_in[10];
  bf16_t* ws = (bf16_t*)d_ws;
  float* fws = (float*)(ws + E_END);
  float* scores_ws = fws + F_SCORES;
  float* mem_ws    = fws + F_MEM;
  float* out = (float*)d_out;

  prep_weights<<<2048, 256, 0, stream>>>(gru_k, gru_rk, W1, Wm, ws);
  xproj_kernel<<<dim3(128, 8), 512, 0, stream>>>(facts, question, gru_b, ws, mem_ws);
  for (int ep = 0; ep < 3; ++ep) {
    scores_kernel<<<dim3(128, 8), 256, 0, stream>>>(question, b1, W2, b2, ws, mem_ws, scores_ws);
    scan_kernel<<<128, 512, 0, stream>>>(question, bm, ws, scores_ws, mem_ws, out, ep == 2);
  }
}